// Round 1
// baseline (470.732 us; speedup 1.0000x reference)
//
#include <hip/hip_runtime.h>

// Problem constants
#define B_SZ 65536
#define NH   100

typedef __bf16 bf16_t;
typedef __bf16 bf16x8 __attribute__((ext_vector_type(8)));
typedef float  f32x4  __attribute__((ext_vector_type(4)));

// ---- d_ws bf16 fragment-layout offsets (elements) ----
// B-fragment order for v_mfma_f32_16x16x32_bf16: for tile (nt,kc), lane (Q=lane>>4,c=lane&15)
// holds W[kc*32 + Q*8 + j][nt*16 + c], j=0..7 contiguous -> idx = ((nt*KC+kc)*64+lane)*8+j
#define SZ_W2 16384   // NT=8, KC=4  (K=128pad x N=128pad)
#define SZ_W3 8192    // NT=4, KC=4  (K=128pad x N=64)
#define SZ_W1 8192    // NT=8, KC=2  (K=64 x N=128pad) per net per block
#define OFF_W2S 0
#define OFF_W2T 16384
#define OFF_W3S 32768
#define OFF_W3T 40960
#define OFF_W1  49152          // block b: s at OFF_W1 + b*2*SZ_W1, t at +SZ_W1
#define WS_TOTAL 163840        // 320 KB of bf16

__global__ void prep_weights(const float* __restrict__ sW1, const float* __restrict__ sW2,
                             const float* __restrict__ sW3, const float* __restrict__ tW1,
                             const float* __restrict__ tW2, const float* __restrict__ tW3,
                             bf16_t* __restrict__ ws) {
  int idx = blockIdx.x * 256 + threadIdx.x;
  if (idx >= WS_TOTAL) return;
  float v;
  if (idx < 32768) {                       // W2: [100,100] -> K128 x N128 frags
    const float* W = (idx < 16384) ? sW2 : tW2;
    int local = idx & 16383;
    int j = local & 7, ln = (local >> 3) & 63, kc = (local >> 9) & 3, nt = local >> 11;
    int k = kc * 32 + (ln >> 4) * 8 + j;
    int n = nt * 16 + (ln & 15);
    v = (k < NH && n < NH) ? W[k * NH + n] : 0.f;
  } else if (idx < 49152) {                // W3: [100,64] -> K128 x N64 frags
    int local = idx - 32768;
    const float* W = (local < 8192) ? sW3 : tW3;
    local &= 8191;
    int j = local & 7, ln = (local >> 3) & 63, kc = (local >> 9) & 3, nt = local >> 11;
    int k = kc * 32 + (ln >> 4) * 8 + j;
    int n = nt * 16 + (ln & 15);
    v = (k < NH) ? W[k * 64 + n] : 0.f;
  } else {                                 // W1 blocks 0..6: [64,100] -> K64 x N128 frags
    int local = idx - 49152;
    int b  = local >> 14;                  // block (z-dim) 0..6
    int r2 = local & 16383;
    const float* W = (r2 < 8192) ? sW1 : tW1;
    int within = r2 & 8191;
    int j = within & 7, ln = (within >> 3) & 63, kc = (within >> 9) & 1, nt = within >> 10;
    int k = kc * 32 + (ln >> 4) * 8 + j;   // 0..63
    int n = nt * 16 + (ln & 15);
    v = (n < NH) ? W[(b * 64 + k) * NH + n] : 0.f;
  }
  ws[idx] = (bf16_t)v;
}

// Main kernel: 512 WGs x 256 threads; each wave owns 32 batch rows (2 m-tiles).
// LDS: 32 KB weight-fragment stage + per-wave 16x136 bf16 h/z transpose buffer.
__global__ __launch_bounds__(256, 1) void flow_kernel(
    const float* __restrict__ e,
    const float* __restrict__ sb1, const float* __restrict__ sb2, const float* __restrict__ sb3,
    const float* __restrict__ tb1, const float* __restrict__ tb2, const float* __restrict__ tb3,
    const bf16_t* __restrict__ wf,
    float* __restrict__ out) {
  __shared__ __align__(16) bf16_t wstage[16384];        // 32 KB
  __shared__ __align__(16) bf16_t hbuf[4][16 * 136];    // stride 136: 2-way bank alias (free), 16B-aligned rows

  const int tid  = threadIdx.x;
  const int wave = tid >> 6;
  const int lane = tid & 63;
  const int c    = lane & 15;   // C/D col, A-frag m-row
  const int Q    = lane >> 4;   // quad
  const int rowBase = blockIdx.x * 128 + wave * 32;

  bf16_t* const myh = &hbuf[wave][0];

  auto stage = [&](int off_elems) {  // copy 16384 bf16 (32 KB) ws -> wstage
    const uint4* src = (const uint4*)(wf + off_elems);
    uint4* dst = (uint4*)wstage;
    #pragma unroll
    for (int it = 0; it < 8; ++it) dst[tid + it * 256] = src[tid + it * 256];
  };

  // persistent incremental layer-1 pre-activations (+b1), both nets
  f32x4 acc1S[2][8], acc1T[2][8];
  #pragma unroll
  for (int nt = 0; nt < 8; ++nt) {
    const int n = nt * 16 + c;
    const float b1s = (n < NH) ? sb1[n] : 0.f;
    const float b1t = (n < NH) ? tb1[n] : 0.f;
    const f32x4 vs = {b1s, b1s, b1s, b1s};
    const f32x4 vt = {b1t, b1t, b1t, b1t};
    #pragma unroll
    for (int mt = 0; mt < 2; ++mt) { acc1S[mt][nt] = vs; acc1T[mt][nt] = vt; }
  }
  float ldacc[2][4] = {0.f, 0.f, 0.f, 0.f, 0.f, 0.f, 0.f, 0.f};

  // h = relu(accIn) -> LDS (C-layout write) -> A-frags; then acc2 = h @ Wfrag + bias
  auto run_l2 = [&](const f32x4 (&accIn)[2][8], const float* __restrict__ b2, f32x4 (&acc2)[2][8]) {
    bf16x8 af[2][4];
    #pragma unroll
    for (int mt = 0; mt < 2; ++mt) {
      #pragma unroll
      for (int nt = 0; nt < 8; ++nt)
        #pragma unroll
        for (int r = 0; r < 4; ++r)
          myh[(Q * 4 + r) * 136 + nt * 16 + c] = (bf16_t)fmaxf(accIn[mt][nt][r], 0.f);
      #pragma unroll
      for (int kc = 0; kc < 4; ++kc)
        af[mt][kc] = *(const bf16x8*)(myh + c * 136 + kc * 32 + Q * 8);
    }
    #pragma unroll
    for (int nt = 0; nt < 8; ++nt) {
      const int n = nt * 16 + c;
      const float bv = (n < NH) ? b2[n] : 0.f;
      const f32x4 bvec = {bv, bv, bv, bv};
      acc2[0][nt] = bvec; acc2[1][nt] = bvec;
    }
    #pragma unroll
    for (int nt = 0; nt < 8; ++nt)
      #pragma unroll
      for (int kc = 0; kc < 4; ++kc) {
        const bf16x8 bfr = *(const bf16x8*)(wstage + ((nt * 4 + kc) * 64 + lane) * 8);
        #pragma unroll
        for (int mt = 0; mt < 2; ++mt)
          acc2[mt][nt] = __builtin_amdgcn_mfma_f32_16x16x32_bf16(af[mt][kc], bfr, acc2[mt][nt], 0, 0, 0);
      }
  };

  auto run_l3 = [&](const f32x4 (&acc2)[2][8], const float* __restrict__ b3, int wbase, f32x4 (&acc3)[2][4]) {
    bf16x8 af[2][4];
    #pragma unroll
    for (int mt = 0; mt < 2; ++mt) {
      #pragma unroll
      for (int nt = 0; nt < 8; ++nt)
        #pragma unroll
        for (int r = 0; r < 4; ++r)
          myh[(Q * 4 + r) * 136 + nt * 16 + c] = (bf16_t)fmaxf(acc2[mt][nt][r], 0.f);
      #pragma unroll
      for (int kc = 0; kc < 4; ++kc)
        af[mt][kc] = *(const bf16x8*)(myh + c * 136 + kc * 32 + Q * 8);
    }
    #pragma unroll
    for (int nt = 0; nt < 4; ++nt) {
      const float bv = b3[nt * 16 + c];
      const f32x4 bvec = {bv, bv, bv, bv};
      acc3[0][nt] = bvec; acc3[1][nt] = bvec;
    }
    #pragma unroll
    for (int nt = 0; nt < 4; ++nt)
      #pragma unroll
      for (int kc = 0; kc < 4; ++kc) {
        const bf16x8 bfr = *(const bf16x8*)(wstage + wbase + ((nt * 4 + kc) * 64 + lane) * 8);
        #pragma unroll
        for (int mt = 0; mt < 2; ++mt)
          acc3[mt][nt] = __builtin_amdgcn_mfma_f32_16x16x32_bf16(af[mt][kc], bfr, acc3[mt][nt], 0, 0, 0);
      }
  };

  for (int i = 0; i < 8; ++i) {
    f32x4 acc2S[2][8], acc2T[2][8];
    __syncthreads();
    stage(OFF_W2S);
    __syncthreads();
    run_l2(acc1S, sb2, acc2S);

    __syncthreads();
    stage(OFF_W2T);
    __syncthreads();
    run_l2(acc1T, tb2, acc2T);

    __syncthreads();
    stage(OFF_W3S);            // stages W3S and W3T (adjacent, 2*SZ_W3 = 16384)
    __syncthreads();
    f32x4 acc3S[2][4], acc3T[2][4];
    run_l3(acc2S, sb3, 0, acc3S);
    run_l3(acc2T, tb3, SZ_W3, acc3T);

    // ---- epilogue: s,t = sigmoid; z = exp(s)*e + t; logdet += sum(s) ----
    bf16x8 zfa[2][2];
    #pragma unroll
    for (int mt = 0; mt < 2; ++mt) {
      #pragma unroll
      for (int r = 0; r < 4; ++r) {
        const int gr = rowBase + mt * 16 + Q * 4 + r;
        const int ebase = gr * 512 + i * 64;
        float ssum = 0.f;
        #pragma unroll
        for (int nt = 0; nt < 4; ++nt) {
          const int col = nt * 16 + c;
          const float sv = 1.f / (1.f + __expf(-acc3S[mt][nt][r]));
          const float tv = 1.f / (1.f + __expf(-acc3T[mt][nt][r]));
          const float ev = e[ebase + col];
          const float zv = __expf(sv) * ev + tv;
          out[ebase + col] = zv;
          myh[(Q * 4 + r) * 136 + col] = (bf16_t)zv;
          ssum += sv;
        }
        ssum += __shfl_xor(ssum, 1);
        ssum += __shfl_xor(ssum, 2);
        ssum += __shfl_xor(ssum, 4);
        ssum += __shfl_xor(ssum, 8);
        ldacc[mt][r] += ssum;
      }
      #pragma unroll
      for (int kc = 0; kc < 2; ++kc)
        zfa[mt][kc] = *(const bf16x8*)(myh + c * 136 + kc * 32 + Q * 8);
    }

    // ---- incremental layer-1 update: acc1 += z_i @ W1[block i] ----
    if (i < 7) {
      __syncthreads();
      stage(OFF_W1 + i * 2 * SZ_W1);   // s block then t block
      __syncthreads();
      #pragma unroll
      for (int nt = 0; nt < 8; ++nt)
        #pragma unroll
        for (int kc = 0; kc < 2; ++kc) {
          const bf16x8 bS = *(const bf16x8*)(wstage + ((nt * 2 + kc) * 64 + lane) * 8);
          const bf16x8 bT = *(const bf16x8*)(wstage + SZ_W1 + ((nt * 2 + kc) * 64 + lane) * 8);
          #pragma unroll
          for (int mt = 0; mt < 2; ++mt) {
            acc1S[mt][nt] = __builtin_amdgcn_mfma_f32_16x16x32_bf16(zfa[mt][kc], bS, acc1S[mt][nt], 0, 0, 0);
            acc1T[mt][nt] = __builtin_amdgcn_mfma_f32_16x16x32_bf16(zfa[mt][kc], bT, acc1T[mt][nt], 0, 0, 0);
          }
        }
    }
  }

  // log_det: row sums held (replicated) per 16-lane group; lane c==0 writes
  if (c == 0) {
    #pragma unroll
    for (int mt = 0; mt < 2; ++mt)
      #pragma unroll
      for (int r = 0; r < 4; ++r)
        out[B_SZ * 512 + rowBase + mt * 16 + Q * 4 + r] = ldacc[mt][r];
  }
}

extern "C" void kernel_launch(void* const* d_in, const int* in_sizes, int n_in,
                              void* d_out, int out_size, void* d_ws, size_t ws_size,
                              hipStream_t stream) {
  (void)in_sizes; (void)n_in; (void)out_size; (void)ws_size;
  const float* e   = (const float*)d_in[0];
  // d_in[1] is C (fixed strict-upper-triangular structure; encoded in the algorithm)
  const float* sW1 = (const float*)d_in[2];
  const float* sb1 = (const float*)d_in[3];
  const float* sW2 = (const float*)d_in[4];
  const float* sb2 = (const float*)d_in[5];
  const float* sW3 = (const float*)d_in[6];
  const float* sb3 = (const float*)d_in[7];
  const float* tW1 = (const float*)d_in[8];
  const float* tb1 = (const float*)d_in[9];
  const float* tW2 = (const float*)d_in[10];
  const float* tb2 = (const float*)d_in[11];
  const float* tW3 = (const float*)d_in[12];
  const float* tb3 = (const float*)d_in[13];
  bf16_t* ws = (bf16_t*)d_ws;            // needs 320 KB
  float* out = (float*)d_out;

  prep_weights<<<WS_TOTAL / 256, 256, 0, stream>>>(sW1, sW2, sW3, tW1, tW2, tW3, ws);
  flow_kernel<<<512, 256, 0, stream>>>(e, sb1, sb2, sb3, tb1, tb2, tb3, ws, out);
}

// Round 2
// 364.557 us; speedup vs baseline: 1.2912x; 1.2912x over previous
//
#include <hip/hip_runtime.h>

// Problem constants
#define B_SZ 65536
#define NH   100

typedef __bf16 bf16_t;
typedef __bf16 bf16x8 __attribute__((ext_vector_type(8)));
typedef float  f32x4  __attribute__((ext_vector_type(4)));

// ---- d_ws bf16 fragment layout (elements), N padded to 112 (7 n-tiles) ----
// frag f=(nt*KC+kc): lane holds W[kc*32+Q*8+j][nt*16+c], j contiguous (b128)
#define SZ_W2 14336            // 7nt * 4kc * 512
#define SZ_W3 8192             // 4nt * 4kc * 512
#define SZ_W1 7168             // 7nt * 2kc * 512 (per net per z-block)
#define OFF_W3   28672         // after W2S,W2T
#define OFF_W1   45056         // after W3S,W3T; block b: S at +b*2*SZ_W1, T at +SZ_W1
#define WS_TOTAL 145408        // elements (290816 bytes)

__global__ void prep_weights(const float* __restrict__ sW1, const float* __restrict__ sW2,
                             const float* __restrict__ sW3, const float* __restrict__ tW1,
                             const float* __restrict__ tW2, const float* __restrict__ tW3,
                             bf16_t* __restrict__ ws) {
  int idx = blockIdx.x * 256 + threadIdx.x;
  if (idx >= WS_TOTAL) return;
  float v = 0.f;
  if (idx < 2 * SZ_W2) {                    // W2: [100,100] -> K128 x N112 frags
    const float* W = (idx < SZ_W2) ? sW2 : tW2;
    int l = idx & (SZ_W2 - 1) & 16383;      // SZ_W2=14336 not pow2; do it properly:
    l = (idx < SZ_W2) ? idx : idx - SZ_W2;
    int j = l & 7, ln = (l >> 3) & 63, kc = (l >> 9) & 3, nt = l >> 11;   // nt 0..6
    int k = kc * 32 + (ln >> 4) * 8 + j;
    int n = nt * 16 + (ln & 15);
    v = (k < NH && n < NH) ? W[k * NH + n] : 0.f;
  } else if (idx < OFF_W1) {                // W3: [100,64] -> K128 x N64 frags
    int l = idx - OFF_W3;
    const float* W = (l < SZ_W3) ? sW3 : tW3;
    l &= (SZ_W3 - 1);
    int j = l & 7, ln = (l >> 3) & 63, kc = (l >> 9) & 3, nt = l >> 11;   // nt 0..3
    int k = kc * 32 + (ln >> 4) * 8 + j;
    int n = nt * 16 + (ln & 15);
    v = (k < NH) ? W[k * 64 + n] : 0.f;
  } else {                                  // W1 blocks 0..6: [64,100] -> K64 x N112 frags
    int l = idx - OFF_W1;
    int b = l / (2 * SZ_W1);
    int r2 = l - b * 2 * SZ_W1;
    const float* W = (r2 < SZ_W1) ? sW1 : tW1;
    int w = (r2 < SZ_W1) ? r2 : r2 - SZ_W1;
    int j = w & 7, ln = (w >> 3) & 63, kc = (w >> 9) & 1, nt = w >> 10;   // nt 0..6
    int k = kc * 32 + (ln >> 4) * 8 + j;    // 0..63
    int n = nt * 16 + (ln & 15);
    v = (n < NH) ? W[(b * 64 + k) * NH + n] : 0.f;
  }
  ws[idx] = (bf16_t)v;
}

// async global->LDS 16B per lane: gptr per-lane, lptr wave-uniform base (+lane*16 implicit)
__device__ __forceinline__ void gload_lds16(const void* gptr, void* lptr) {
  __builtin_amdgcn_global_load_lds(
      (const __attribute__((address_space(1))) unsigned int*)gptr,
      (__attribute__((address_space(3))) unsigned int*)lptr, 16, 0, 0);
}

struct __align__(16) SMem {
  bf16_t w2[2 * SZ_W2];   // S at 0, T at SZ_W2           (57344 B)
  bf16_t w3[2 * SZ_W3];   // S at 0, T at SZ_W3           (32768 B)
  bf16_t w1[2 * SZ_W1];   // current block: S, T          (28672 B)
  bf16_t hb[4][16 * 136]; // per-wave transpose buffer    (17408 B)
};                        // total 136192 B (133 KB) -> 1 block/CU

// 512 blocks x 256 threads; each wave owns 32 batch rows (2 m-tiles). 2 generations/CU.
__global__ __launch_bounds__(256, 1) void flow_kernel(
    const float* __restrict__ e,
    const float* __restrict__ sb1, const float* __restrict__ sb2, const float* __restrict__ sb3,
    const float* __restrict__ tb1, const float* __restrict__ tb2, const float* __restrict__ tb3,
    const bf16_t* __restrict__ wf,
    float* __restrict__ out) {
  __shared__ SMem sm;

  const int tid  = threadIdx.x;
  const int wave = tid >> 6;
  const int lane = tid & 63;
  const int c    = lane & 15;   // C/D col, A-frag m-row
  const int Q    = lane >> 4;   // quad
  const int rowBase = blockIdx.x * 128 + wave * 32;

  bf16_t* const myh = &sm.hb[wave][0];

  // ---- initial load: W2S,W2T,W3S,W3T,W1(block0) = contiguous 118784 B = 116 KB chunks
  {
    const char* g = (const char*)wf;
    char* l = (char*)&sm;
    #pragma unroll
    for (int t = 0; t < 29; ++t) {
      const int ch = wave * 29 + t;
      gload_lds16(g + ch * 1024 + lane * 16, l + ch * 1024);
    }
  }

  // ---- bias registers ----
  float b2S[7], b2T[7], b3S[4], b3T[4];
  #pragma unroll
  for (int nt = 0; nt < 7; ++nt) {
    const int n = nt * 16 + c;
    b2S[nt] = (n < NH) ? sb2[n] : 0.f;
    b2T[nt] = (n < NH) ? tb2[n] : 0.f;
  }
  #pragma unroll
  for (int nt = 0; nt < 4; ++nt) { b3S[nt] = sb3[nt * 16 + c]; b3T[nt] = tb3[nt * 16 + c]; }

  // persistent incremental layer-1 pre-activations (+b1), both nets
  f32x4 acc1S[2][7], acc1T[2][7];
  #pragma unroll
  for (int nt = 0; nt < 7; ++nt) {
    const int n = nt * 16 + c;
    const float b1s = (n < NH) ? sb1[n] : 0.f;
    const float b1t = (n < NH) ? tb1[n] : 0.f;
    const f32x4 vs = {b1s, b1s, b1s, b1s};
    const f32x4 vt = {b1t, b1t, b1t, b1t};
    #pragma unroll
    for (int mt = 0; mt < 2; ++mt) { acc1S[mt][nt] = vs; acc1T[mt][nt] = vt; }
  }
  float ldacc[2][4] = {0.f, 0.f, 0.f, 0.f, 0.f, 0.f, 0.f, 0.f};

  __syncthreads();   // initial weights + W1 block0 resident

  // one net: acc1 -> relu -> LDS -> A-frags -> L2 -> relu -> LDS -> A-frags -> L3 -> acc3
  auto run_net = [&](const f32x4 (&acc1)[2][7], const bf16_t* __restrict__ w2f,
                     const bf16_t* __restrict__ w3f, const float (&b2r)[7],
                     const float (&b3r)[4], f32x4 (&acc3)[2][4]) {
    f32x4 acc2[2][7];
    bf16x8 af[2][4];
    // L2 A-feed (h1), zero-pad cols 112..127 for the kc=3 chunk
    #pragma unroll
    for (int mt = 0; mt < 2; ++mt) {
      #pragma unroll
      for (int nt = 0; nt < 7; ++nt)
        #pragma unroll
        for (int r = 0; r < 4; ++r)
          myh[(Q * 4 + r) * 136 + nt * 16 + c] = (bf16_t)fmaxf(acc1[mt][nt][r], 0.f);
      #pragma unroll
      for (int r = 0; r < 4; ++r)
        myh[(Q * 4 + r) * 136 + 112 + c] = (bf16_t)0.f;
      #pragma unroll
      for (int kc = 0; kc < 4; ++kc)
        af[mt][kc] = *(const bf16x8*)(myh + c * 136 + kc * 32 + Q * 8);
    }
    #pragma unroll
    for (int nt = 0; nt < 7; ++nt) {
      const f32x4 bv = {b2r[nt], b2r[nt], b2r[nt], b2r[nt]};
      acc2[0][nt] = bv; acc2[1][nt] = bv;
    }
    #pragma unroll
    for (int nt = 0; nt < 7; ++nt)
      #pragma unroll
      for (int kc = 0; kc < 4; ++kc) {
        const bf16x8 bfr = *(const bf16x8*)(w2f + ((nt * 4 + kc) * 64 + lane) * 8);
        #pragma unroll
        for (int mt = 0; mt < 2; ++mt)
          acc2[mt][nt] = __builtin_amdgcn_mfma_f32_16x16x32_bf16(af[mt][kc], bfr, acc2[mt][nt], 0, 0, 0);
      }
    // L3 A-feed (h2); pad cols stay zero from h1 write
    #pragma unroll
    for (int mt = 0; mt < 2; ++mt) {
      #pragma unroll
      for (int nt = 0; nt < 7; ++nt)
        #pragma unroll
        for (int r = 0; r < 4; ++r)
          myh[(Q * 4 + r) * 136 + nt * 16 + c] = (bf16_t)fmaxf(acc2[mt][nt][r], 0.f);
      #pragma unroll
      for (int kc = 0; kc < 4; ++kc)
        af[mt][kc] = *(const bf16x8*)(myh + c * 136 + kc * 32 + Q * 8);
    }
    #pragma unroll
    for (int nt = 0; nt < 4; ++nt) {
      const f32x4 bv = {b3r[nt], b3r[nt], b3r[nt], b3r[nt]};
      acc3[0][nt] = bv; acc3[1][nt] = bv;
    }
    #pragma unroll
    for (int nt = 0; nt < 4; ++nt)
      #pragma unroll
      for (int kc = 0; kc < 4; ++kc) {
        const bf16x8 bfr = *(const bf16x8*)(w3f + ((nt * 4 + kc) * 64 + lane) * 8);
        #pragma unroll
        for (int mt = 0; mt < 2; ++mt)
          acc3[mt][nt] = __builtin_amdgcn_mfma_f32_16x16x32_bf16(af[mt][kc], bfr, acc3[mt][nt], 0, 0, 0);
      }
  };

  for (int i = 0; i < 8; ++i) {
    // prefetch e for this step into registers (consumed in epilogue, ~2 GEMMs later)
    float ev[2][4][4];
    #pragma unroll
    for (int mt = 0; mt < 2; ++mt)
      #pragma unroll
      for (int r = 0; r < 4; ++r) {
        const int ebase = (rowBase + mt * 16 + Q * 4 + r) * 512 + i * 64;
        #pragma unroll
        for (int nt = 0; nt < 4; ++nt)
          ev[mt][r][nt] = e[ebase + nt * 16 + c];
      }

    f32x4 acc3S[2][4], acc3T[2][4];
    run_net(acc1S, sm.w2,         sm.w3,         b2S, b3S, acc3S);
    run_net(acc1T, sm.w2 + SZ_W2, sm.w3 + SZ_W3, b2T, b3T, acc3T);

    // ---- epilogue: s,t = sigmoid; z = exp(s)*e + t; logdet += sum(s) ----
    bf16x8 zfa[2][2];
    #pragma unroll
    for (int mt = 0; mt < 2; ++mt) {
      #pragma unroll
      for (int r = 0; r < 4; ++r) {
        const int obase = (rowBase + mt * 16 + Q * 4 + r) * 512 + i * 64;
        float ssum = 0.f;
        #pragma unroll
        for (int nt = 0; nt < 4; ++nt) {
          const int col = nt * 16 + c;
          const float sv = 1.f / (1.f + __expf(-acc3S[mt][nt][r]));
          const float tv = 1.f / (1.f + __expf(-acc3T[mt][nt][r]));
          const float zv = __expf(sv) * ev[mt][r][nt] + tv;
          __builtin_nontemporal_store(zv, &out[obase + col]);
          myh[(Q * 4 + r) * 136 + col] = (bf16_t)zv;
          ssum += sv;
        }
        ssum += __shfl_xor(ssum, 1);
        ssum += __shfl_xor(ssum, 2);
        ssum += __shfl_xor(ssum, 4);
        ssum += __shfl_xor(ssum, 8);
        ldacc[mt][r] += ssum;
      }
      #pragma unroll
      for (int kc = 0; kc < 2; ++kc)
        zfa[mt][kc] = *(const bf16x8*)(myh + c * 136 + kc * 32 + Q * 8);
    }

    // ---- incremental layer-1 update: acc1 += z_i @ W1[block i] ----
    if (i < 7) {
      __syncthreads();   // W1 block i prefetch (issued last step / init) is resident
      #pragma unroll
      for (int nt = 0; nt < 7; ++nt)
        #pragma unroll
        for (int kc = 0; kc < 2; ++kc) {
          const bf16x8 bS = *(const bf16x8*)(sm.w1 + ((nt * 2 + kc) * 64 + lane) * 8);
          const bf16x8 bT = *(const bf16x8*)(sm.w1 + SZ_W1 + ((nt * 2 + kc) * 64 + lane) * 8);
          #pragma unroll
          for (int mt = 0; mt < 2; ++mt) {
            acc1S[mt][nt] = __builtin_amdgcn_mfma_f32_16x16x32_bf16(zfa[mt][kc], bS, acc1S[mt][nt], 0, 0, 0);
            acc1T[mt][nt] = __builtin_amdgcn_mfma_f32_16x16x32_bf16(zfa[mt][kc], bT, acc1T[mt][nt], 0, 0, 0);
          }
        }
      __syncthreads();   // all waves done reading W1 block i
      if (i < 6) {       // prefetch W1 block i+1; hides under next step's L2/L3
        const char* g = (const char*)(wf + OFF_W1 + (i + 1) * 2 * SZ_W1);
        char* l = (char*)sm.w1;
        #pragma unroll
        for (int t = 0; t < 7; ++t) {
          const int ch = wave * 7 + t;
          gload_lds16(g + ch * 1024 + lane * 16, l + ch * 1024);
        }
      }
    }
  }

  // log_det: per (mt,r) replicated across 16 c-lanes; lane c==0 writes
  if (c == 0) {
    #pragma unroll
    for (int mt = 0; mt < 2; ++mt)
      #pragma unroll
      for (int r = 0; r < 4; ++r)
        out[B_SZ * 512 + rowBase + mt * 16 + Q * 4 + r] = ldacc[mt][r];
  }
}

extern "C" void kernel_launch(void* const* d_in, const int* in_sizes, int n_in,
                              void* d_out, int out_size, void* d_ws, size_t ws_size,
                              hipStream_t stream) {
  (void)in_sizes; (void)n_in; (void)out_size; (void)ws_size;
  const float* e   = (const float*)d_in[0];
  // d_in[1] is C (fixed strict-upper-triangular structure; encoded in the algorithm)
  const float* sW1 = (const float*)d_in[2];
  const float* sb1 = (const float*)d_in[3];
  const float* sW2 = (const float*)d_in[4];
  const float* sb2 = (const float*)d_in[5];
  const float* sW3 = (const float*)d_in[6];
  const float* sb3 = (const float*)d_in[7];
  const float* tW1 = (const float*)d_in[8];
  const float* tb1 = (const float*)d_in[9];
  const float* tW2 = (const float*)d_in[10];
  const float* tb2 = (const float*)d_in[11];
  const float* tW3 = (const float*)d_in[12];
  const float* tb3 = (const float*)d_in[13];
  bf16_t* ws = (bf16_t*)d_ws;            // needs 284 KB
  float* out = (float*)d_out;

  prep_weights<<<(WS_TOTAL + 255) / 256, 256, 0, stream>>>(sW1, sW2, sW3, tW1, tW2, tW3, ws);
  flow_kernel<<<512, 256, 0, stream>>>(e, sb1, sb2, sb3, tb1, tb2, tb3, ws, out);
}